// Round 11
// baseline (9982.735 us; speedup 1.0000x reference)
//
#include <hip/hip_runtime.h>
#include <stdint.h>

#define T_STEPS 4096
#define HID     768
#define G3      2304      // 3*HID
#define NBLK    192       // scan blocks
#define NTHR    192       // threads per scan block
#define UPB     4         // hidden units per block (192*4 = 768)
#define FAST_SWEEPS 512   // bounded sc1 dwordx4 poll sweeps before sticky fallback

typedef unsigned int uintv4 __attribute__((ext_vector_type(4)));

// ---------------- threefry2x32 (matches jax._src.prng exactly) ----------------
__device__ __forceinline__ void threefry2x32(uint32_t k0, uint32_t k1,
                                             uint32_t x0, uint32_t x1,
                                             uint32_t* o0, uint32_t* o1) {
  uint32_t ks[3] = {k0, k1, k0 ^ k1 ^ 0x1BD11BDAu};
  x0 += ks[0]; x1 += ks[1];
  const int r0[4] = {13, 15, 26, 6};
  const int r1[4] = {17, 29, 16, 24};
#pragma unroll
  for (int i = 0; i < 5; ++i) {
    const int* rr = (i & 1) ? r1 : r0;
#pragma unroll
    for (int j = 0; j < 4; ++j) {
      x0 += x1;
      x1 = (x1 << rr[j]) | (x1 >> (32 - rr[j]));
      x1 ^= x0;
    }
    x0 += ks[(i + 1) % 3];
    x1 += ks[(i + 2) % 3] + (uint32_t)(i + 1);
  }
  *o0 = x0; *o1 = x1;
}

__device__ __forceinline__ float gumbel_from_bits(uint32_t bits) {
  float f = __uint_as_float((bits >> 9) | 0x3f800000u) - 1.0f;
  float u = fmaxf(f, 1.17549435e-38f);
  return -logf(-logf(u));
}

// fast gates: overflow-safe (inf algebra collapses correctly)
__device__ __forceinline__ float fast_sigmoid(float x) {
  return 1.0f / (1.0f + __expf(-x));
}
__device__ __forceinline__ float fast_tanh(float x) {
  float e = __expf(2.0f * x);          // inf for large x, 0 for very negative
  return 1.0f - 2.0f / (e + 1.0f);     // -> 1 and -1 at the limits
}

// ---------------- init: pair buffer 0 = (h0, tag 0), buffer 1 = tag -1 ----------
__global__ void init_pairs(const float* __restrict__ h0,
                           unsigned long long* __restrict__ pairs) {
  int j = threadIdx.x;
  if (j < HID) {
    pairs[j]       = (unsigned long long)__float_as_uint(h0[j]);   // tag 0 high word
    pairs[HID + j] = 0xFFFFFFFF00000000ull;                        // tag -1
  }
}

// ---------------- GEMM: xi = inputs(4096x768) @ Wi(768x2304) + bi  (fp32) ------
__launch_bounds__(256)
__global__ void gemm_xi(const float* __restrict__ A, const float* __restrict__ B,
                        const float* __restrict__ bias, float* __restrict__ C) {
  const int N = G3, K = HID;
  __shared__ __align__(16) float As[8][128];
  __shared__ __align__(16) float Bs[8][128];
  int tid = threadIdx.x;
  int bn = blockIdx.x * 128;
  int bm = blockIdx.y * 128;
  int tx = tid & 15, ty = tid >> 4;

  float acc[8][8];
#pragma unroll
  for (int i = 0; i < 8; ++i)
#pragma unroll
    for (int j = 0; j < 8; ++j) acc[i][j] = 0.f;

  const int ar = tid >> 1;
  const int ac = (tid & 1) * 4;
  const int br = tid >> 5;
  const int bc = (tid & 31) * 4;
  const float* Aptr = A + (size_t)(bm + ar) * K + ac;
  const float* Bptr = B + (size_t)br * N + bn + bc;

  for (int k0 = 0; k0 < K; k0 += 8) {
    float4 av = *(const float4*)(Aptr + k0);
    float4 bv = *(const float4*)(Bptr + (size_t)k0 * N);
    As[ac + 0][ar] = av.x; As[ac + 1][ar] = av.y;
    As[ac + 2][ar] = av.z; As[ac + 3][ar] = av.w;
    *(float4*)&Bs[br][bc] = bv;
    __syncthreads();
#pragma unroll
    for (int kk = 0; kk < 8; ++kk) {
      float a[8], b[8];
      *(float4*)&a[0] = *(const float4*)&As[kk][ty * 8];
      *(float4*)&a[4] = *(const float4*)&As[kk][ty * 8 + 4];
      *(float4*)&b[0] = *(const float4*)&Bs[kk][tx * 8];
      *(float4*)&b[4] = *(const float4*)&Bs[kk][tx * 8 + 4];
#pragma unroll
      for (int i = 0; i < 8; ++i)
#pragma unroll
        for (int j = 0; j < 8; ++j) acc[i][j] = fmaf(a[i], b[j], acc[i][j]);
    }
    __syncthreads();
  }
#pragma unroll
  for (int i = 0; i < 8; ++i) {
    float* crow = C + (size_t)(bm + ty * 8 + i) * N + bn + tx * 8;
    const float* brow = bias + bn + tx * 8;
#pragma unroll
    for (int j = 0; j < 8; ++j) crow[j] = acc[i][j] + brow[j];
  }
}

// ---------------- persistent GRU scan (round-10 + detect/barrier trims) ----------
// Structure identical to rounds 2/10. Changes vs round 10:
//  (a) BOTH 16B poll halves issued back-to-back, ONE s_waitcnt vmcnt(0):
//      one MALL round trip per sweep instead of two (detect period halved).
//  (b) third (end-of-loop) __syncthreads removed -- redundant: deposits at t+1
//      hit the opposite h_lds parity half; deposits at t+2 are program-order
//      after barrier2_t on the depositing thread; next iteration's post-poll
//      barrier orders this iteration's dots reads vs next dots writes.
__launch_bounds__(NTHR)
__global__ void gru_scan(const float* __restrict__ xi, const float* __restrict__ Wh,
                         const float* __restrict__ bhn,
                         unsigned long long* __restrict__ pairs,
                         float* __restrict__ y) {
  __shared__ __align__(16) float h_lds[16 * 52];   // 48-chunk per l, padded to 52
  __shared__ float dots[12];

  const int tid = threadIdx.x;
  const int b = blockIdx.x;
  const int g = tid >> 4;      // column group 0..11
  const int l = tid & 15;      // lane within group
  const int u0 = b * UPB;

  const int C = (g < 4) ? (u0 + g)
              : (g < 8) ? (HID + u0 + (g - 4))
                        : (2 * HID + u0 + (g - 8));

  float w[48];
#pragma unroll
  for (int i = 0; i < 48; ++i) w[i] = Wh[(size_t)(l * 48 + i) * G3 + C];

  float bhn_u = 0.f;
  if (tid < UPB) bhn_u = bhn[u0 + tid];

  const int base_k = tid * 4;   // this thread transports h[base_k .. base_k+3]
  bool use_fb = false;          // sticky fallback to per-pair atomic poll

  for (int t = 0; t < T_STEPS; ++t) {
    unsigned long long* buf = pairs + (size_t)(t & 1) * HID;

    // xi prefetch (independent of h -> completes under the poll)
    float xr = 0.f, xz = 0.f, xn = 0.f;
    if (tid < UPB) {
      const float* xrow = xi + (size_t)t * G3;
      xr = xrow[u0 + tid];
      xz = xrow[HID + u0 + tid];
      xn = xrow[2 * HID + u0 + tid];
    }

    // ---- poll own 4 pairs (one 32B producer publish) until all tags == t ----
    {
      const unsigned long long* p = &buf[base_k];
      bool done = false;
      if (!use_fb) {
        int it = 0;
        do {
          uintv4 q, q2;
          asm volatile("global_load_dwordx4 %0, %2, off sc1\n\t"
                       "global_load_dwordx4 %1, %3, off sc1\n\t"
                       "s_waitcnt vmcnt(0)"
                       : "=&v"(q), "=&v"(q2)
                       : "v"(p), "v"(p + 2) : "memory");
          if (q[1] == (unsigned int)t && q[3] == (unsigned int)t &&
              q2[1] == (unsigned int)t && q2[3] == (unsigned int)t) {
            int k = base_k;
            h_lds[k + 0 + 4 * ((k + 0) / 48)] = __uint_as_float(q[0]);
            h_lds[k + 1 + 4 * ((k + 1) / 48)] = __uint_as_float(q[2]);
            h_lds[k + 2 + 4 * ((k + 2) / 48)] = __uint_as_float(q2[0]);
            h_lds[k + 3 + 4 * ((k + 3) / 48)] = __uint_as_float(q2[2]);
            done = true;
            break;
          }
        } while (++it < FAST_SWEEPS);
        if (!done) use_fb = true;   // sticky: distrust the fast path from now on
      }
      if (!done) {
        // proven r2 poll: per-pair relaxed AGENT atomic loads
        unsigned int got = 0;
        while (got != 0xFu) {
#pragma unroll
          for (int c = 0; c < 4; ++c) {
            if (!(got & (1u << c))) {
              unsigned long long v = __hip_atomic_load(&buf[base_k + c],
                                                       __ATOMIC_RELAXED,
                                                       __HIP_MEMORY_SCOPE_AGENT);
              if ((int)(v >> 32) == t) {
                int k = base_k + c;
                h_lds[k + 4 * (k / 48)] = __uint_as_float((unsigned int)v);
                got |= (1u << c);
              }
            }
          }
        }
      }
    }
    __syncthreads();   // barrier1: deposits visible to all

    // matvec: dot(h, Wh[:,C]) with 4 independent fp32 chains
    float a0 = 0.f, a1 = 0.f, a2 = 0.f, a3 = 0.f;
    const float4* hp = (const float4*)&h_lds[52 * l];
#pragma unroll
    for (int i = 0; i < 12; ++i) {
      float4 h4 = hp[i];
      a0 = fmaf(w[4 * i + 0], h4.x, a0);
      a1 = fmaf(w[4 * i + 1], h4.y, a1);
      a2 = fmaf(w[4 * i + 2], h4.z, a2);
      a3 = fmaf(w[4 * i + 3], h4.w, a3);
    }
    float acc = (a0 + a1) + (a2 + a3);
    acc += __shfl_xor(acc, 8, 16);
    acc += __shfl_xor(acc, 4, 16);
    acc += __shfl_xor(acc, 2, 16);
    acc += __shfl_xor(acc, 1, 16);
    if (l == 0) dots[g] = acc;

    float hprev = 0.f;
    if (tid < UPB) {
      int j = u0 + tid;
      hprev = h_lds[j + 4 * (j / 48)];
    }
    __syncthreads();   // barrier2: dots visible; also orders h_lds reads vs t+2 deposits

    if (tid < UPB) {
      float hr = dots[tid], hz = dots[4 + tid], hn = dots[8 + tid];
      float r = fast_sigmoid(xr + hr);
      float z = fast_sigmoid(xz + hz);
      float n = fast_tanh(xn + r * (hn + bhn_u));
      float hnew = (1.f - z) * n + z * hprev;
      int j = u0 + tid;
      unsigned long long pv =
          (((unsigned long long)(unsigned int)(t + 1)) << 32) | __float_as_uint(hnew);
      __hip_atomic_store(&pairs[(size_t)((t + 1) & 1) * HID + j], pv, __ATOMIC_RELAXED,
                         __HIP_MEMORY_SCOPE_AGENT);     // publish FIRST
      y[(size_t)t * HID + j] = hnew;
    }
    // no third barrier: next iteration's barrier1 provides the dots write/read
    // ordering, and cross-step h_lds reuse is ordered by barrier2 (see header)
  }
}

// ---------------- decode: out = y@Wd + bd ; action = argmax(out[:, :2] + gumbel) ---
__launch_bounds__(256)
__global__ void decode_out(const float* __restrict__ y, const float* __restrict__ Wd,
                           const float* __restrict__ bd, float* __restrict__ out) {
  int tid = threadIdx.x;
  int lane = tid & 63;
  int wid = tid >> 6;
  int r = blockIdx.x * 4 + wid;
  const float* yr = y + (size_t)r * HID;

  float acc0 = 0.f, acc1 = 0.f, acc2 = 0.f, acc3 = 0.f;
#pragma unroll
  for (int i = 0; i < 12; ++i) {
    int k = lane + 64 * i;
    float yv = yr[k];
    float4 wd = *(const float4*)&Wd[(size_t)k * 4];
    acc0 = fmaf(yv, wd.x, acc0);
    acc1 = fmaf(yv, wd.y, acc1);
    acc2 = fmaf(yv, wd.z, acc2);
    acc3 = fmaf(yv, wd.w, acc3);
    if (r == T_STEPS - 1) out[20480 + k] = yv;   // final_h
  }
#pragma unroll
  for (int m = 32; m >= 1; m >>= 1) {
    acc0 += __shfl_xor(acc0, m, 64);
    acc1 += __shfl_xor(acc1, m, 64);
    acc2 += __shfl_xor(acc2, m, 64);
    acc3 += __shfl_xor(acc3, m, 64);
  }
  if (lane == 0) {
    float o0 = acc0 + bd[0], o1 = acc1 + bd[1], o2 = acc2 + bd[2], o3 = acc3 + bd[3];
    out[(size_t)r * 4 + 0] = o0;
    out[(size_t)r * 4 + 1] = o1;
    out[(size_t)r * 4 + 2] = o2;
    out[(size_t)r * 4 + 3] = o3;

    // jax PRNG, threefry_partitionable (verified round 2)
    uint32_t ak0, ak1;
    threefry2x32(0u, 42u, 0u, 1u, &ak0, &ak1);
    uint32_t s0, s1;
    threefry2x32(ak0, ak1, 0u, (uint32_t)(2 * r), &s0, &s1);
    uint32_t g0bits = s0 ^ s1;
    threefry2x32(ak0, ak1, 0u, (uint32_t)(2 * r + 1), &s0, &s1);
    uint32_t g1bits = s0 ^ s1;

    float gg0 = gumbel_from_bits(g0bits);
    float gg1 = gumbel_from_bits(g1bits);
    int action = (o1 + gg1 > o0 + gg0) ? 1 : 0;
    out[16384 + r] = (float)action;
  }
}

// ---------------- launch -----------------------------------------------------------
extern "C" void kernel_launch(void* const* d_in, const int* in_sizes, int n_in,
                              void* d_out, int out_size, void* d_ws, size_t ws_size,
                              hipStream_t stream) {
  const float* inputs = (const float*)d_in[0];
  const float* h0     = (const float*)d_in[1];
  const float* Wi     = (const float*)d_in[2];
  const float* bi     = (const float*)d_in[3];
  const float* Wh     = (const float*)d_in[4];
  const float* bhn    = (const float*)d_in[5];
  const float* Wd     = (const float*)d_in[6];
  const float* bd     = (const float*)d_in[7];
  float* out = (float*)d_out;

  char* ws = (char*)d_ws;
  unsigned long long* pairs = (unsigned long long*)ws;              // 2*768*8 = 12 KB
  float* xi = (float*)(ws + 16384);                                 // 4096*2304*4
  float* y  = (float*)(ws + 16384 + (size_t)T_STEPS * G3 * 4);      // 4096*768*4

  hipLaunchKernelGGL(init_pairs, dim3(1), dim3(HID), 0, stream, h0, pairs);
  hipLaunchKernelGGL(gemm_xi, dim3(G3 / 128, T_STEPS / 128), dim3(256), 0, stream,
                     inputs, Wi, bi, xi);

  {
    const float* xi_c = xi;
    const float* wh_c = Wh;
    const float* bhn_c = bhn;
    unsigned long long* pr = pairs;
    float* y_p = y;
    void* args[] = { (void*)&xi_c, (void*)&wh_c, (void*)&bhn_c, (void*)&pr, (void*)&y_p };
    hipError_t e = hipLaunchCooperativeKernel((const void*)gru_scan, dim3(NBLK),
                                              dim3(NTHR), args, 0, stream);
    if (e != hipSuccess) {
      hipLaunchKernelGGL(gru_scan, dim3(NBLK), dim3(NTHR), 0, stream,
                         xi_c, wh_c, bhn_c, pr, y_p);
    }
  }

  hipLaunchKernelGGL(decode_out, dim3(T_STEPS / 4), dim3(256), 0, stream, y, Wd, bd, out);
}

// Round 12
// 9173.959 us; speedup vs baseline: 1.0882x; 1.0882x over previous
//
#include <hip/hip_runtime.h>
#include <stdint.h>

#define T_STEPS 4096
#define HID     768
#define G3      2304      // 3*HID
#define NBLK    192       // scan blocks
#define NTHR    192       // threads per scan block
#define UPB     4         // hidden units per block (192*4 = 768)
#define FAST_SWEEPS 512   // bounded sc1 dwordx4 poll sweeps before sticky fallback

typedef unsigned int uintv4 __attribute__((ext_vector_type(4)));

// ---------------- threefry2x32 (matches jax._src.prng exactly) ----------------
__device__ __forceinline__ void threefry2x32(uint32_t k0, uint32_t k1,
                                             uint32_t x0, uint32_t x1,
                                             uint32_t* o0, uint32_t* o1) {
  uint32_t ks[3] = {k0, k1, k0 ^ k1 ^ 0x1BD11BDAu};
  x0 += ks[0]; x1 += ks[1];
  const int r0[4] = {13, 15, 26, 6};
  const int r1[4] = {17, 29, 16, 24};
#pragma unroll
  for (int i = 0; i < 5; ++i) {
    const int* rr = (i & 1) ? r1 : r0;
#pragma unroll
    for (int j = 0; j < 4; ++j) {
      x0 += x1;
      x1 = (x1 << rr[j]) | (x1 >> (32 - rr[j]));
      x1 ^= x0;
    }
    x0 += ks[(i + 1) % 3];
    x1 += ks[(i + 2) % 3] + (uint32_t)(i + 1);
  }
  *o0 = x0; *o1 = x1;
}

__device__ __forceinline__ float gumbel_from_bits(uint32_t bits) {
  float f = __uint_as_float((bits >> 9) | 0x3f800000u) - 1.0f;
  float u = fmaxf(f, 1.17549435e-38f);
  return -logf(-logf(u));
}

// fast gates: overflow-safe (inf algebra collapses correctly)
__device__ __forceinline__ float fast_sigmoid(float x) {
  return 1.0f / (1.0f + __expf(-x));
}
__device__ __forceinline__ float fast_tanh(float x) {
  float e = __expf(2.0f * x);          // inf for large x, 0 for very negative
  return 1.0f - 2.0f / (e + 1.0f);     // -> 1 and -1 at the limits
}

// ---------------- init: pair buffer 0 = (h0, tag 0), buffer 1 = tag -1 ----------
__global__ void init_pairs(const float* __restrict__ h0,
                           unsigned long long* __restrict__ pairs) {
  int j = threadIdx.x;
  if (j < HID) {
    pairs[j]       = (unsigned long long)__float_as_uint(h0[j]);   // tag 0 high word
    pairs[HID + j] = 0xFFFFFFFF00000000ull;                        // tag -1
  }
}

// ---------------- GEMM: xi = inputs(4096x768) @ Wi(768x2304) + bi  (fp32) ------
__launch_bounds__(256)
__global__ void gemm_xi(const float* __restrict__ A, const float* __restrict__ B,
                        const float* __restrict__ bias, float* __restrict__ C) {
  const int N = G3, K = HID;
  __shared__ __align__(16) float As[8][128];
  __shared__ __align__(16) float Bs[8][128];
  int tid = threadIdx.x;
  int bn = blockIdx.x * 128;
  int bm = blockIdx.y * 128;
  int tx = tid & 15, ty = tid >> 4;

  float acc[8][8];
#pragma unroll
  for (int i = 0; i < 8; ++i)
#pragma unroll
    for (int j = 0; j < 8; ++j) acc[i][j] = 0.f;

  const int ar = tid >> 1;
  const int ac = (tid & 1) * 4;
  const int br = tid >> 5;
  const int bc = (tid & 31) * 4;
  const float* Aptr = A + (size_t)(bm + ar) * K + ac;
  const float* Bptr = B + (size_t)br * N + bn + bc;

  for (int k0 = 0; k0 < K; k0 += 8) {
    float4 av = *(const float4*)(Aptr + k0);
    float4 bv = *(const float4*)(Bptr + (size_t)k0 * N);
    As[ac + 0][ar] = av.x; As[ac + 1][ar] = av.y;
    As[ac + 2][ar] = av.z; As[ac + 3][ar] = av.w;
    *(float4*)&Bs[br][bc] = bv;
    __syncthreads();
#pragma unroll
    for (int kk = 0; kk < 8; ++kk) {
      float a[8], b[8];
      *(float4*)&a[0] = *(const float4*)&As[kk][ty * 8];
      *(float4*)&a[4] = *(const float4*)&As[kk][ty * 8 + 4];
      *(float4*)&b[0] = *(const float4*)&Bs[kk][tx * 8];
      *(float4*)&b[4] = *(const float4*)&Bs[kk][tx * 8 + 4];
#pragma unroll
      for (int i = 0; i < 8; ++i)
#pragma unroll
        for (int j = 0; j < 8; ++j) acc[i][j] = fmaf(a[i], b[j], acc[i][j]);
    }
    __syncthreads();
  }
#pragma unroll
  for (int i = 0; i < 8; ++i) {
    float* crow = C + (size_t)(bm + ty * 8 + i) * N + bn + tx * 8;
    const float* brow = bias + bn + tx * 8;
#pragma unroll
    for (int j = 0; j < 8; ++j) crow[j] = acc[i][j] + brow[j];
  }
}

// ---------------- persistent GRU scan (round-10 champion, final) -----------------
// Structure identical to round 2 (192 blocks x 192 thr, LDS deposit, 2 barriers,
// (value,tag) parity pairs at relaxed AGENT scope). Round-10 trims:
//  (a) poll reads 32B/thread via global_load_dwordx4 sc1 (agent/MALL coherent),
//      serialized halves (measured faster than paired-issue, r11); bounded
//      sticky fallback to the proven per-pair atomic poll (no-hang, r4 lesson).
//  (b) fast __expf-based gates on the serial tail.
//  (c) publish the (h,tag) pair before the y store.
//  (d) third barrier retained (removing it regressed slightly, r11).
__launch_bounds__(NTHR)
__global__ void gru_scan(const float* __restrict__ xi, const float* __restrict__ Wh,
                         const float* __restrict__ bhn,
                         unsigned long long* __restrict__ pairs,
                         float* __restrict__ y) {
  __shared__ __align__(16) float h_lds[16 * 52];   // 48-chunk per l, padded to 52
  __shared__ float dots[12];

  const int tid = threadIdx.x;
  const int b = blockIdx.x;
  const int g = tid >> 4;      // column group 0..11
  const int l = tid & 15;      // lane within group
  const int u0 = b * UPB;

  const int C = (g < 4) ? (u0 + g)
              : (g < 8) ? (HID + u0 + (g - 4))
                        : (2 * HID + u0 + (g - 8));

  float w[48];
#pragma unroll
  for (int i = 0; i < 48; ++i) w[i] = Wh[(size_t)(l * 48 + i) * G3 + C];

  float bhn_u = 0.f;
  if (tid < UPB) bhn_u = bhn[u0 + tid];

  const int base_k = tid * 4;   // this thread transports h[base_k .. base_k+3]
  bool use_fb = false;          // sticky fallback to per-pair atomic poll

  for (int t = 0; t < T_STEPS; ++t) {
    unsigned long long* buf = pairs + (size_t)(t & 1) * HID;

    // xi prefetch (independent of h -> completes under the poll)
    float xr = 0.f, xz = 0.f, xn = 0.f;
    if (tid < UPB) {
      const float* xrow = xi + (size_t)t * G3;
      xr = xrow[u0 + tid];
      xz = xrow[HID + u0 + tid];
      xn = xrow[2 * HID + u0 + tid];
    }

    // ---- poll own 4 pairs (one 32B producer publish) until all tags == t ----
    {
      const unsigned long long* p = &buf[base_k];
      bool done = false;
      if (!use_fb) {
        int it = 0;
        do {
          uintv4 q;
          asm volatile("global_load_dwordx4 %0, %1, off sc1\n\t"
                       "s_waitcnt vmcnt(0)"
                       : "=&v"(q) : "v"(p) : "memory");
          if (q[1] == (unsigned int)t && q[3] == (unsigned int)t) {
            // second 16B half
            uintv4 q2;
            asm volatile("global_load_dwordx4 %0, %1, off sc1\n\t"
                         "s_waitcnt vmcnt(0)"
                         : "=&v"(q2) : "v"(p + 2) : "memory");
            if (q2[1] == (unsigned int)t && q2[3] == (unsigned int)t) {
              int k = base_k;
              h_lds[k + 0 + 4 * ((k + 0) / 48)] = __uint_as_float(q[0]);
              h_lds[k + 1 + 4 * ((k + 1) / 48)] = __uint_as_float(q[2]);
              h_lds[k + 2 + 4 * ((k + 2) / 48)] = __uint_as_float(q2[0]);
              h_lds[k + 3 + 4 * ((k + 3) / 48)] = __uint_as_float(q2[2]);
              done = true;
              break;
            }
          }
        } while (++it < FAST_SWEEPS);
        if (!done) use_fb = true;   // sticky: distrust the fast path from now on
      }
      if (!done) {
        // proven r2 poll: per-pair relaxed AGENT atomic loads
        unsigned int got = 0;
        while (got != 0xFu) {
#pragma unroll
          for (int c = 0; c < 4; ++c) {
            if (!(got & (1u << c))) {
              unsigned long long v = __hip_atomic_load(&buf[base_k + c],
                                                       __ATOMIC_RELAXED,
                                                       __HIP_MEMORY_SCOPE_AGENT);
              if ((int)(v >> 32) == t) {
                int k = base_k + c;
                h_lds[k + 4 * (k / 48)] = __uint_as_float((unsigned int)v);
                got |= (1u << c);
              }
            }
          }
        }
      }
    }
    __syncthreads();

    // matvec: dot(h, Wh[:,C]) with 4 independent fp32 chains
    float a0 = 0.f, a1 = 0.f, a2 = 0.f, a3 = 0.f;
    const float4* hp = (const float4*)&h_lds[52 * l];
#pragma unroll
    for (int i = 0; i < 12; ++i) {
      float4 h4 = hp[i];
      a0 = fmaf(w[4 * i + 0], h4.x, a0);
      a1 = fmaf(w[4 * i + 1], h4.y, a1);
      a2 = fmaf(w[4 * i + 2], h4.z, a2);
      a3 = fmaf(w[4 * i + 3], h4.w, a3);
    }
    float acc = (a0 + a1) + (a2 + a3);
    acc += __shfl_xor(acc, 8, 16);
    acc += __shfl_xor(acc, 4, 16);
    acc += __shfl_xor(acc, 2, 16);
    acc += __shfl_xor(acc, 1, 16);
    if (l == 0) dots[g] = acc;

    float hprev = 0.f;
    if (tid < UPB) {
      int j = u0 + tid;
      hprev = h_lds[j + 4 * (j / 48)];
    }
    __syncthreads();

    if (tid < UPB) {
      float hr = dots[tid], hz = dots[4 + tid], hn = dots[8 + tid];
      float r = fast_sigmoid(xr + hr);
      float z = fast_sigmoid(xz + hz);
      float n = fast_tanh(xn + r * (hn + bhn_u));
      float hnew = (1.f - z) * n + z * hprev;
      int j = u0 + tid;
      unsigned long long pv =
          (((unsigned long long)(unsigned int)(t + 1)) << 32) | __float_as_uint(hnew);
      __hip_atomic_store(&pairs[(size_t)((t + 1) & 1) * HID + j], pv, __ATOMIC_RELAXED,
                         __HIP_MEMORY_SCOPE_AGENT);     // publish FIRST
      y[(size_t)t * HID + j] = hnew;
    }
    __syncthreads();   // protect h_lds/dots from next iteration's writers
  }
}

// ---------------- decode: out = y@Wd + bd ; action = argmax(out[:, :2] + gumbel) ---
__launch_bounds__(256)
__global__ void decode_out(const float* __restrict__ y, const float* __restrict__ Wd,
                           const float* __restrict__ bd, float* __restrict__ out) {
  int tid = threadIdx.x;
  int lane = tid & 63;
  int wid = tid >> 6;
  int r = blockIdx.x * 4 + wid;
  const float* yr = y + (size_t)r * HID;

  float acc0 = 0.f, acc1 = 0.f, acc2 = 0.f, acc3 = 0.f;
#pragma unroll
  for (int i = 0; i < 12; ++i) {
    int k = lane + 64 * i;
    float yv = yr[k];
    float4 wd = *(const float4*)&Wd[(size_t)k * 4];
    acc0 = fmaf(yv, wd.x, acc0);
    acc1 = fmaf(yv, wd.y, acc1);
    acc2 = fmaf(yv, wd.z, acc2);
    acc3 = fmaf(yv, wd.w, acc3);
    if (r == T_STEPS - 1) out[20480 + k] = yv;   // final_h
  }
#pragma unroll
  for (int m = 32; m >= 1; m >>= 1) {
    acc0 += __shfl_xor(acc0, m, 64);
    acc1 += __shfl_xor(acc1, m, 64);
    acc2 += __shfl_xor(acc2, m, 64);
    acc3 += __shfl_xor(acc3, m, 64);
  }
  if (lane == 0) {
    float o0 = acc0 + bd[0], o1 = acc1 + bd[1], o2 = acc2 + bd[2], o3 = acc3 + bd[3];
    out[(size_t)r * 4 + 0] = o0;
    out[(size_t)r * 4 + 1] = o1;
    out[(size_t)r * 4 + 2] = o2;
    out[(size_t)r * 4 + 3] = o3;

    // jax PRNG, threefry_partitionable (verified round 2)
    uint32_t ak0, ak1;
    threefry2x32(0u, 42u, 0u, 1u, &ak0, &ak1);
    uint32_t s0, s1;
    threefry2x32(ak0, ak1, 0u, (uint32_t)(2 * r), &s0, &s1);
    uint32_t g0bits = s0 ^ s1;
    threefry2x32(ak0, ak1, 0u, (uint32_t)(2 * r + 1), &s0, &s1);
    uint32_t g1bits = s0 ^ s1;

    float gg0 = gumbel_from_bits(g0bits);
    float gg1 = gumbel_from_bits(g1bits);
    int action = (o1 + gg1 > o0 + gg0) ? 1 : 0;
    out[16384 + r] = (float)action;
  }
}

// ---------------- launch -----------------------------------------------------------
extern "C" void kernel_launch(void* const* d_in, const int* in_sizes, int n_in,
                              void* d_out, int out_size, void* d_ws, size_t ws_size,
                              hipStream_t stream) {
  const float* inputs = (const float*)d_in[0];
  const float* h0     = (const float*)d_in[1];
  const float* Wi     = (const float*)d_in[2];
  const float* bi     = (const float*)d_in[3];
  const float* Wh     = (const float*)d_in[4];
  const float* bhn    = (const float*)d_in[5];
  const float* Wd     = (const float*)d_in[6];
  const float* bd     = (const float*)d_in[7];
  float* out = (float*)d_out;

  char* ws = (char*)d_ws;
  unsigned long long* pairs = (unsigned long long*)ws;              // 2*768*8 = 12 KB
  float* xi = (float*)(ws + 16384);                                 // 4096*2304*4
  float* y  = (float*)(ws + 16384 + (size_t)T_STEPS * G3 * 4);      // 4096*768*4

  hipLaunchKernelGGL(init_pairs, dim3(1), dim3(HID), 0, stream, h0, pairs);
  hipLaunchKernelGGL(gemm_xi, dim3(G3 / 128, T_STEPS / 128), dim3(256), 0, stream,
                     inputs, Wi, bi, xi);

  {
    const float* xi_c = xi;
    const float* wh_c = Wh;
    const float* bhn_c = bhn;
    unsigned long long* pr = pairs;
    float* y_p = y;
    void* args[] = { (void*)&xi_c, (void*)&wh_c, (void*)&bhn_c, (void*)&pr, (void*)&y_p };
    hipError_t e = hipLaunchCooperativeKernel((const void*)gru_scan, dim3(NBLK),
                                              dim3(NTHR), args, 0, stream);
    if (e != hipSuccess) {
      hipLaunchKernelGGL(gru_scan, dim3(NBLK), dim3(NTHR), 0, stream,
                         xi_c, wh_c, bhn_c, pr, y_p);
    }
  }

  hipLaunchKernelGGL(decode_out, dim3(T_STEPS / 4), dim3(256), 0, stream, y, Wd, bd, out);
}